// Round 5
// baseline (142.800 us; speedup 1.0000x reference)
//
#include <hip/hip_runtime.h>

// FocalBCELoss: loss = -mean( t*log(p)*(1-p)^2*alpha[c] + (1-t)*log(1-p)*p^2 )
// N=262144, C=64, GAMMA=2.  t in {0,1} exactly =>
//   term = log(q)*w,  q = t?p:(1-p),  w = t?(1-p)^2*a : p^2   (one v_log_f32/elem)
//
// R5: discriminate per-wave vs per-CU read clamp. Flat 16-deep NT prefetch:
// every thread issues all 8 P + 8 T nontemporal dwordx4 loads back-to-back
// (16 KB per wave in flight), then computes while vmcnt drains incrementally.
// launch_bounds(256,4) -> <=128 VGPRs, ~16 waves/CU.

typedef float v4f __attribute__((ext_vector_type(4)));

constexpr int N_ELEM = 262144 * 64;       // 16,777,216
constexpr int N_VEC4 = N_ELEM / 4;        // 4,194,304 float4s
constexpr int BLOCK  = 256;
constexpr int GRID1  = 2048;
constexpr int STRIDE = GRID1 * BLOCK;     // 524,288 float4s (== 0 mod 64 elems)
constexpr int ITERS  = N_VEC4 / STRIDE;   // 8 float4s per thread per array

__device__ __forceinline__ float focal_term(float p, float t, float a) {
    float u  = 1.0f - p;
    float d  = p - u;                       // 2p-1
    float q  = fmaf(t, d, u);               // t? p : 1-p   (exact: t in {0,1})
    float lg = __logf(q);                   // single fast log
    float wa = u * u * a;                   // t=1 weight
    float pp = p * p;                       // t=0 weight
    float w  = fmaf(t, wa - pp, pp);        // t? wa : pp
    return lg * w;
}

__global__ __launch_bounds__(BLOCK, 4) void focal_partial_kernel(
        const v4f* __restrict__ p4,
        const v4f* __restrict__ t4,
        const float*  __restrict__ alpha,
        float* __restrict__ partials) {
    const int tid = blockIdx.x * BLOCK + threadIdx.x;

    // STRIDE*4 and the block tile are both ==0 mod C: each thread's 4 channels
    // are fixed for the whole kernel -> alpha in registers, no LDS.
    const int c0 = (threadIdx.x * 4) & 63;
    const float a0 = alpha[c0 + 0];
    const float a1 = alpha[c0 + 1];
    const float a2 = alpha[c0 + 2];
    const float a3 = alpha[c0 + 3];

    // Issue ALL loads first — 16 NT dwordx4 per thread in flight at once.
    v4f P[ITERS], T[ITERS];
#pragma unroll
    for (int k = 0; k < ITERS; ++k)
        P[k] = __builtin_nontemporal_load(&p4[tid + k * STRIDE]);
#pragma unroll
    for (int k = 0; k < ITERS; ++k)
        T[k] = __builtin_nontemporal_load(&t4[tid + k * STRIDE]);

    float acc0 = 0.0f, acc1 = 0.0f;
#pragma unroll
    for (int k = 0; k < ITERS; ++k) {
        acc0 += focal_term(P[k].x, T[k].x, a0);
        acc0 += focal_term(P[k].y, T[k].y, a1);
        acc1 += focal_term(P[k].z, T[k].z, a2);
        acc1 += focal_term(P[k].w, T[k].w, a3);
    }
    float acc = acc0 + acc1;

    // wave64 shuffle reduce
    for (int off = 32; off > 0; off >>= 1)
        acc += __shfl_down(acc, off, 64);

    __shared__ float s_wave[BLOCK / 64];
    const int lane = threadIdx.x & 63;
    const int wid  = threadIdx.x >> 6;
    if (lane == 0) s_wave[wid] = acc;
    __syncthreads();
    if (threadIdx.x == 0)
        partials[blockIdx.x] = s_wave[0] + s_wave[1] + s_wave[2] + s_wave[3];
}

__global__ __launch_bounds__(BLOCK) void focal_final_kernel(
        const float* __restrict__ partials,
        float* __restrict__ out) {
    double acc = 0.0;
    for (int i = threadIdx.x; i < GRID1; i += BLOCK)
        acc += (double)partials[i];

    for (int off = 32; off > 0; off >>= 1)
        acc += __shfl_down(acc, off, 64);

    __shared__ double s_wave[BLOCK / 64];
    const int lane = threadIdx.x & 63;
    const int wid  = threadIdx.x >> 6;
    if (lane == 0) s_wave[wid] = acc;
    __syncthreads();
    if (threadIdx.x == 0) {
        double total = s_wave[0] + s_wave[1] + s_wave[2] + s_wave[3];
        out[0] = (float)(-total / (double)N_ELEM);
    }
}

extern "C" void kernel_launch(void* const* d_in, const int* in_sizes, int n_in,
                              void* d_out, int out_size, void* d_ws, size_t ws_size,
                              hipStream_t stream) {
    const v4f*  p4    = (const v4f*)d_in[0];    // inputs  [N,C] fp32
    const v4f*  t4    = (const v4f*)d_in[1];    // targets [N,C] fp32
    const float* alpha = (const float*)d_in[2]; // alpha   [C]   fp32
    float* out      = (float*)d_out;
    float* partials = (float*)d_ws;             // GRID1 floats, fully rewritten each call

    focal_partial_kernel<<<GRID1, BLOCK, 0, stream>>>(p4, t4, alpha, partials);
    focal_final_kernel<<<1, BLOCK, 0, stream>>>(partials, out);
}